// Round 6
// baseline (58.900 us; speedup 1.0000x reference)
//
#include <hip/hip_runtime.h>

// FOFE encoding:
//   out[w, c] = sum over positions k with x[w,k]==c && c!=0 of f^(#nonzero strictly after k)
// x: [num_words, 32] int32, f: scalar f32, out: [num_words, 256] f32.
//
// Structure: one-shot waves, no grid-stride loop. 8192 blocks x 4 waves;
// each wave handles exactly 8 words as TWO quads (4 words each). Pipelining
// is inter-block: a wave retires with its nt stores still draining, freeing
// the slot for a fresh wave whose loads overlap the drain — no VGPR-reuse
// vmcnt stalls, no loop prologue/epilogue. Output stores are nontemporal
// (write-once 268 MB stream bypasses L2); x loads are nontemporal too.
// Per quad: one int2 load per lane covers 4 words' chars; 4 wave-private
// 256-float LDS tiles; no block barriers (DS pipe in-order per wave).

constexpr int WORD_LEN = 32;
constexpr int VOCAB    = 256;
constexpr int WAVES_PER_BLOCK = 4;    // 256 threads
constexpr int WORDS_PER_WAVE  = 8;

typedef float f32x4 __attribute__((ext_vector_type(4)));
typedef int   i32x2 __attribute__((ext_vector_type(2)));

__global__ __launch_bounds__(256) void fofe_kernel(
    const int* __restrict__ x,
    const float* __restrict__ fptr,
    float* __restrict__ out,
    int num_words)
{
    // [wave][word-in-quad][vocab] : 16 KiB per block; both quads use the
    // tiles sequentially (DS program order keeps it safe without barriers)
    __shared__ float tiles[WAVES_PER_BLOCK][4][VOCAB];

    const int lane = threadIdx.x & 63;
    const int wv   = threadIdx.x >> 6;
    const int grp  = lane >> 4;          // which word of the quad (0..3)
    const int j    = lane & 15;          // char-pair index: positions 2j, 2j+1

    const int gw = blockIdx.x * WAVES_PER_BLOCK + wv;      // global wave id
    const int w0 = gw * WORDS_PER_WAVE;                    // first word

    const i32x2* x2 = reinterpret_cast<const i32x2*>(x);   // 16 i32x2 per word

    // ---- issue both quads' char loads immediately (nt, read-once) ----
    i32x2 cA = (i32x2)(0), cB = (i32x2)(0);
    if (w0 + grp < num_words)
        cA = __builtin_nontemporal_load(&x2[(size_t)w0 * 16 + lane]);
    if (w0 + 4 + grp < num_words)
        cB = __builtin_nontemporal_load(&x2[(size_t)(w0 + 4) * 16 + lane]);

    const float f  = *fptr;
    const float lf = __log2f(f);

    float (*mytiles)[VOCAB] = tiles[wv];
    float*  tile = mytiles[grp];                            // this lane's word tile
    f32x4*  t4   = reinterpret_cast<f32x4*>(mytiles);       // 256 f32x4 (all 4 tiles)

    // process one quad of 4 words whose chars this wave holds in `c`
    auto process = [&](int wq, i32x2 c) {
        const bool nzE = (c.x != 0);
        const bool nzO = (c.y != 0);
        const unsigned long long mE = __ballot(nzE);
        const unsigned long long mO = __ballot(nzO);
        const unsigned int mEg = (unsigned int)(mE >> (grp * 16)) & 0xFFFFu;
        const unsigned int mOg = (unsigned int)(mO >> (grp * 16)) & 0xFFFFu;
        // nonzeros strictly after position 2j / 2j+1 within this word:
        const int sE = __popc(mEg >> (j + 1)) + __popc(mOg >> j);
        const int sO = __popc(mEg >> (j + 1)) + __popc(mOg >> (j + 1));

        float wE = 0.0f, wO = 0.0f;
        if (nzE) wE = (sE == 0) ? 1.0f : exp2f((float)sE * lf);
        if (nzO) wO = (sO == 0) ? 1.0f : exp2f((float)sO * lf);

        // zero all 4 tiles: 4 KiB = 4 x ds_write_b128 per lane
        const f32x4 z = (f32x4)(0.0f);
        t4[lane]       = z;
        t4[lane + 64]  = z;
        t4[lane + 128] = z;
        t4[lane + 192] = z;

        // scatter (wave-private tiles; DS pipe in-order => no barrier)
        if (nzE) atomicAdd(&tile[c.x], wE);
        if (nzO) atomicAdd(&tile[c.y], wO);

        // read back & stream out 4 KiB contiguous, fully coalesced, nt
        const f32x4 v0 = t4[lane];
        const f32x4 v1 = t4[lane + 64];
        const f32x4 v2 = t4[lane + 128];
        const f32x4 v3 = t4[lane + 192];
        f32x4* o4 = reinterpret_cast<f32x4*>(out + (size_t)wq * VOCAB);
        if (wq + 0 < num_words) __builtin_nontemporal_store(v0, &o4[lane]);
        if (wq + 1 < num_words) __builtin_nontemporal_store(v1, &o4[lane + 64]);
        if (wq + 2 < num_words) __builtin_nontemporal_store(v2, &o4[lane + 128]);
        if (wq + 3 < num_words) __builtin_nontemporal_store(v3, &o4[lane + 192]);
    };

    process(w0, cA);
    process(w0 + 4, cB);
}

extern "C" void kernel_launch(void* const* d_in, const int* in_sizes, int n_in,
                              void* d_out, int out_size, void* d_ws, size_t ws_size,
                              hipStream_t stream)
{
    const int*   x    = (const int*)d_in[0];
    const float* fptr = (const float*)d_in[1];
    float*       out  = (float*)d_out;

    const int num_words = in_sizes[0] / WORD_LEN;
    const int waves  = (num_words + WORDS_PER_WAVE - 1) / WORDS_PER_WAVE;
    const int blocks = (waves + WAVES_PER_BLOCK - 1) / WAVES_PER_BLOCK;

    fofe_kernel<<<blocks, 256, 0, stream>>>(x, fptr, out, num_words);
}

// Round 7
// 57.438 us; speedup vs baseline: 1.0254x; 1.0254x over previous
//
#include <hip/hip_runtime.h>

// FOFE encoding:
//   out[w, c] = sum over positions k with x[w,k]==c && c!=0 of f^(#nonzero strictly after k)
// x: [num_words, 32] int32, f: scalar f32, out: [num_words, 256] f32.
//
// Structure: one-shot waves, 4096 blocks x 4 waves, 16 words per wave as
// FOUR quads (4 words each). All four quads' char loads are issued in the
// prologue; the four DS chains (zero -> atomic scatter -> readback) are
// queued back-to-back on the in-order DS pipe, so one stage's readback
// latency hides under the next stages' issue, and counted lgkmcnt waits
// release each stage's nontemporal stores as its reads retire. No vmcnt
// register-reuse coupling anywhere (fresh regs per stage, kernel retires
// with stores draining). LDS safety: stage i's ds_reads are issued before
// stage i+1's ds_writes to the same addresses; the per-wave DS pipe is
// in-order, and tiles are wave-private (no barriers needed).

constexpr int WORD_LEN = 32;
constexpr int VOCAB    = 256;
constexpr int WAVES_PER_BLOCK = 4;    // 256 threads
constexpr int WORDS_PER_WAVE  = 16;   // 4 quads

typedef float f32x4 __attribute__((ext_vector_type(4)));
typedef int   i32x2 __attribute__((ext_vector_type(2)));

__global__ __launch_bounds__(256) void fofe_kernel(
    const int* __restrict__ x,
    const float* __restrict__ fptr,
    float* __restrict__ out,
    int num_words)
{
    // [wave][word-in-quad][vocab] : 16 KiB per block; all 4 stages reuse
    // the same 4 tiles sequentially (DS program order keeps it safe)
    __shared__ float tiles[WAVES_PER_BLOCK][4][VOCAB];

    const int lane = threadIdx.x & 63;
    const int wv   = threadIdx.x >> 6;
    const int grp  = lane >> 4;          // which word of the quad (0..3)
    const int j    = lane & 15;          // char-pair index: positions 2j, 2j+1

    const int gw = blockIdx.x * WAVES_PER_BLOCK + wv;      // global wave id
    const int w0 = gw * WORDS_PER_WAVE;                    // first word

    const i32x2* x2 = reinterpret_cast<const i32x2*>(x);   // 16 i32x2 per word

    // ---- prologue: issue all 4 quads' char loads ----
    i32x2 c[4];
#pragma unroll
    for (int q = 0; q < 4; ++q) {
        c[q] = (i32x2)(0);
        if (w0 + 4 * q + grp < num_words)
            c[q] = x2[(size_t)(w0 + 4 * q) * 16 + lane];
    }

    const float f  = *fptr;
    const float lf = __log2f(f);

    float (*mytiles)[VOCAB] = tiles[wv];
    float*  tile = mytiles[grp];                            // this lane's word tile
    f32x4*  t4   = reinterpret_cast<f32x4*>(mytiles);       // 256 f32x4 (all 4 tiles)

    // ---- four independent stages, queued back-to-back on the DS pipe ----
#pragma unroll
    for (int q = 0; q < 4; ++q) {
        const int wq = w0 + 4 * q;
        const i32x2 cc = c[q];

        const bool nzE = (cc.x != 0);
        const bool nzO = (cc.y != 0);
        const unsigned long long mE = __ballot(nzE);
        const unsigned long long mO = __ballot(nzO);
        const unsigned int mEg = (unsigned int)(mE >> (grp * 16)) & 0xFFFFu;
        const unsigned int mOg = (unsigned int)(mO >> (grp * 16)) & 0xFFFFu;
        // nonzeros strictly after position 2j / 2j+1 within this word:
        const int sE = __popc(mEg >> (j + 1)) + __popc(mOg >> j);
        const int sO = __popc(mEg >> (j + 1)) + __popc(mOg >> (j + 1));

        float wE = 0.0f, wO = 0.0f;
        if (nzE) wE = (sE == 0) ? 1.0f : exp2f((float)sE * lf);
        if (nzO) wO = (sO == 0) ? 1.0f : exp2f((float)sO * lf);

        // zero all 4 tiles: 4 KiB = 4 x ds_write_b128 per lane
        const f32x4 z = (f32x4)(0.0f);
        t4[lane]       = z;
        t4[lane + 64]  = z;
        t4[lane + 128] = z;
        t4[lane + 192] = z;

        // scatter (wave-private tiles; DS pipe in-order => no barrier)
        if (nzE) atomicAdd(&tile[cc.x], wE);
        if (nzO) atomicAdd(&tile[cc.y], wO);

        // read back & stream out 4 KiB contiguous, fully coalesced, nt
        const f32x4 v0 = t4[lane];
        const f32x4 v1 = t4[lane + 64];
        const f32x4 v2 = t4[lane + 128];
        const f32x4 v3 = t4[lane + 192];
        f32x4* o4 = reinterpret_cast<f32x4*>(out + (size_t)wq * VOCAB);
        if (wq + 0 < num_words) __builtin_nontemporal_store(v0, &o4[lane]);
        if (wq + 1 < num_words) __builtin_nontemporal_store(v1, &o4[lane + 64]);
        if (wq + 2 < num_words) __builtin_nontemporal_store(v2, &o4[lane + 128]);
        if (wq + 3 < num_words) __builtin_nontemporal_store(v3, &o4[lane + 192]);
    }
}

extern "C" void kernel_launch(void* const* d_in, const int* in_sizes, int n_in,
                              void* d_out, int out_size, void* d_ws, size_t ws_size,
                              hipStream_t stream)
{
    const int*   x    = (const int*)d_in[0];
    const float* fptr = (const float*)d_in[1];
    float*       out  = (float*)d_out;

    const int num_words = in_sizes[0] / WORD_LEN;
    const int waves  = (num_words + WORDS_PER_WAVE - 1) / WORDS_PER_WAVE;
    const int blocks = (waves + WAVES_PER_BLOCK - 1) / WAVES_PER_BLOCK;

    fofe_kernel<<<blocks, 256, 0, stream>>>(x, fptr, out, num_words);
}